// Round 1
// baseline (201.278 us; speedup 1.0000x reference)
//
#include <hip/hip_runtime.h>

// SparsemaxBisectLoss: x (8192 x 32000 f32), target (8192 int32) -> scalar f32
//
// Math: sparsemax tau satisfies sum(relu(x - tau)) = 1, tau in [max-1, max-1/d].
// Elements <= max-1 contribute exactly 0 for any tau in the bracket, so only
// candidates { x_i > max-1 } matter (~25-200 of 32000 for N(0,1) rows).
// We stream each row once: chunk-0 block-max gives threshold thr = max0 - 1
// (<= final_max - 1, so candidate set is a SUPERSET of the support), push
// candidates to LDS, then solve tau exactly via Michelot iteration on the
// candidates (exact limit of the reference's 50-step bisection).

#define ROW_LEN 32000
#define ROW_V4  8000      // float4 per row
#define CAP     4096      // candidate capacity (worst plausible row ~1200)

__global__ __launch_bounds__(256) void sparsemax_row_kernel(
    const float* __restrict__ x, const int* __restrict__ target,
    float* __restrict__ row_loss, int n_rows)
{
    __shared__ float s_cand[CAP];
    __shared__ float s_red[4];
    __shared__ int   s_cnt;

    const int row  = blockIdx.x;
    if (row >= n_rows) return;
    const int t    = threadIdx.x;
    const int lane = t & 63;
    const int wid  = t >> 6;

    const float*  rowp = x + (size_t)row * ROW_LEN;
    const float4* rowv = (const float4*)rowp;

    float x_tgt = 0.f;
    if (t == 0) {
        s_cnt = 0;
        x_tgt = rowp[target[row]];   // single gather, latency hidden
    }

    float thr = 0.f;

    // 8 chunks of 1024 float4 (4096 floats); last chunk predicated.
    for (int c = 0; c < 8; ++c) {
        const int base = c * 1024 + t;
        float4 v[4];
        #pragma unroll
        for (int k = 0; k < 4; ++k) {
            const int idx = base + k * 256;
            if (idx < ROW_V4) v[k] = rowv[idx];
            else              v[k] = make_float4(-1e30f, -1e30f, -1e30f, -1e30f);
        }
        if (c == 0) {
            // block max of chunk 0 -> conservative (valid) threshold
            float lm = -1e30f;
            #pragma unroll
            for (int k = 0; k < 4; ++k)
                lm = fmaxf(lm, fmaxf(fmaxf(v[k].x, v[k].y), fmaxf(v[k].z, v[k].w)));
            #pragma unroll
            for (int o = 32; o >= 1; o >>= 1)
                lm = fmaxf(lm, __shfl_xor(lm, o));
            if (lane == 0) s_red[wid] = lm;
            __syncthreads();
            const float bm = fmaxf(fmaxf(s_red[0], s_red[1]),
                                   fmaxf(s_red[2], s_red[3]));
            thr = bm - 1.0f;
        }
        // filter + push (rare: ~30-200 pushes per row total)
        #pragma unroll
        for (int k = 0; k < 4; ++k) {
            const float vals[4] = {v[k].x, v[k].y, v[k].z, v[k].w};
            #pragma unroll
            for (int e = 0; e < 4; ++e) {
                const float val = vals[e];
                if (val > thr) {
                    const int idx = atomicAdd(&s_cnt, 1);
                    if (idx < CAP) s_cand[idx] = val;
                }
            }
        }
    }
    __syncthreads();

    // Epilogue on wave 0 only: exact tau via Michelot, then loss.
    if (wid == 0) {
        int m = s_cnt;
        if (m > CAP) m = CAP;

        float tau = -1e30f;   // first pass includes all candidates
        int c_prev = -1;
        for (int it = 0; it < 100; ++it) {
            float s = 0.f; int cnt = 0;
            for (int j = lane; j < m; j += 64) {
                const float v = s_cand[j];
                if (v > tau) { s += v; cnt++; }
            }
            #pragma unroll
            for (int o = 32; o >= 1; o >>= 1) {
                s   += __shfl_xor(s, o);
                cnt += __shfl_xor(cnt, o);
            }
            const float tau_new = (s - 1.0f) / (float)cnt;
            if (cnt == c_prev) { tau = tau_new; break; }  // active set stable
            c_prev = cnt;
            tau = tau_new;
        }

        float sp = 0.f, sp2 = 0.f, spx = 0.f;
        for (int j = lane; j < m; j += 64) {
            const float v = s_cand[j];
            const float p = v - tau;
            if (p > 0.f) { sp += p; sp2 += p * p; spx += p * v; }
        }
        #pragma unroll
        for (int o = 32; o >= 1; o >>= 1) {
            sp  += __shfl_xor(sp, o);
            sp2 += __shfl_xor(sp2, o);
            spx += __shfl_xor(spx, o);
        }
        if (lane == 0) {
            const float inv  = 1.0f / sp;                 // ensure_sum_one
            const float loss = 0.5f * (1.0f - sp2 * inv * inv)
                             + spx * inv - x_tgt;
            row_loss[row] = loss;
        }
    }
}

// Deterministic mean reduction of n row losses -> out[0]
__global__ __launch_bounds__(256) void mean_kernel(
    const float* __restrict__ row_loss, float* __restrict__ out, int n)
{
    __shared__ float s_red[4];
    const int t = threadIdx.x;
    const int lane = t & 63, wid = t >> 6;
    float s = 0.f;
    for (int i = t; i < n; i += 256) s += row_loss[i];
    #pragma unroll
    for (int o = 32; o >= 1; o >>= 1) s += __shfl_xor(s, o);
    if (lane == 0) s_red[wid] = s;
    __syncthreads();
    if (t == 0)
        out[0] = (s_red[0] + s_red[1] + s_red[2] + s_red[3]) / (float)n;
}

// Fallback path if workspace is too small: accumulate loss/n atomically.
__global__ void zero_out_kernel(float* out) { out[0] = 0.f; }

__global__ __launch_bounds__(256) void sparsemax_row_atomic_wrap(
    const float* __restrict__ x, const int* __restrict__ target,
    float* __restrict__ out, int n_rows);  // not used in primary path

extern "C" void kernel_launch(void* const* d_in, const int* in_sizes, int n_in,
                              void* d_out, int out_size, void* d_ws, size_t ws_size,
                              hipStream_t stream)
{
    const float* x      = (const float*)d_in[0];
    const int*   target = (const int*)d_in[1];
    float*       out    = (float*)d_out;
    const int n_rows = in_sizes[1];          // 8192 (target count)
    float* row_loss = (float*)d_ws;

    // primary path: per-row losses in workspace, then deterministic reduce
    sparsemax_row_kernel<<<n_rows, 256, 0, stream>>>(x, target, row_loss, n_rows);
    mean_kernel<<<1, 256, 0, stream>>>(row_loss, out, n_rows);
}